// Round 1
// baseline (102.137 us; speedup 1.0000x reference)
//
#include <hip/hip_runtime.h>

// Problem constants (from reference)
#define UPDATE_SIZE 4096
#define BATCH 256
#define NUM_UPDATES 8
#define NUM_CH 2
#define KEEP (NUM_UPDATES * UPDATE_SIZE)               // 32768
#define SNAP ((BATCH + NUM_UPDATES - 1) * UPDATE_SIZE) // 1077248
#define OUT_LEN (BATCH * UPDATE_SIZE)                  // 1048576 = 2^20

// float4-unit constants
#define OUT4 (OUT_LEN / 4)          // 262144 = 2^18
#define SNAP4 (SNAP / 4)            // 269312
#define REST4 ((SNAP - OUT_LEN) / 4) // 7168
#define ROW4 (KEEP / 4)             // 8192 float4 per (b,c) update row
#define UPD4 (UPDATE_SIZE / 4)      // 1024
#define TOTAL4 (2 * OUT4 + 2 * SNAP4) // 1062912 = 4152 * 256

__global__ __launch_bounds__(256) void OnlineAverager_62680752718461_kernel(
    const float* __restrict__ update,
    const float* __restrict__ snapshot,
    float* __restrict__ out) {
  const int tid = blockIdx.x * blockDim.x + threadIdx.x;
  if (tid >= TOTAL4) return;

  const float4* __restrict__ up4 = reinterpret_cast<const float4*>(update);
  const float4* __restrict__ sn4 = reinterpret_cast<const float4*>(snapshot);
  float4* __restrict__ o4 = reinterpret_cast<float4*>(out);

  int c, s4;
  bool write_zero = false;

  if (tid < 2 * OUT4) {
    // output tensor region: flat = c*OUT4 + s4
    c = tid >> 18;            // / OUT4
    s4 = tid & (OUT4 - 1);
  } else {
    // new_snapshot region: flat = 2*OUT4 + c*SNAP4 + t4
    const int r = tid - 2 * OUT4;
    c = (r >= SNAP4) ? 1 : 0;
    const int t4 = r - c * SNAP4;
    if (t4 < REST4) {
      s4 = OUT4 + t4;        // acc position past out_len
    } else {
      write_zero = true;     // zero pad of new_snapshot
      s4 = 0;
    }
  }

  float4 acc;
  if (write_zero) {
    acc = make_float4(0.f, 0.f, 0.f, 0.f);
  } else {
    acc = sn4[c * SNAP4 + s4];
    const int q = s4 >> 10;  // s0 >> 12, uniform over the 4 packed elements
    if (q >= 7 && q < BATCH) {
      // interior: exactly 8 covering windows; fully unrolled for ILP
      #pragma unroll
      for (int k = 0; k < 8; ++k) {
        const int b = q - 7 + k;
        const float4 u = up4[(b * NUM_CH + c) * ROW4 + (s4 - b * UPD4)];
        acc.x += 0.125f * u.x;
        acc.y += 0.125f * u.y;
        acc.z += 0.125f * u.z;
        acc.w += 0.125f * u.w;
      }
    } else {
      const int blo = (q >= 7) ? (q - 7) : 0;
      const int bhi = (q < BATCH) ? q : (BATCH - 1);
      for (int b = blo; b <= bhi; ++b) {
        const float4 u = up4[(b * NUM_CH + c) * ROW4 + (s4 - b * UPD4)];
        acc.x += 0.125f * u.x;
        acc.y += 0.125f * u.y;
        acc.z += 0.125f * u.z;
        acc.w += 0.125f * u.w;
      }
    }
  }

  o4[tid] = acc;
}

extern "C" void kernel_launch(void* const* d_in, const int* in_sizes, int n_in,
                              void* d_out, int out_size, void* d_ws, size_t ws_size,
                              hipStream_t stream) {
  const float* update = (const float*)d_in[0];   // (256, 2, 32768) f32
  const float* snapshot = (const float*)d_in[1]; // (2, 1077248) f32
  float* out = (float*)d_out;                    // (1,2,2^20) ++ (2,SNAP) f32

  const int threads = 256;
  const int blocks = (TOTAL4 + threads - 1) / threads; // 4152
  OnlineAverager_62680752718461_kernel<<<blocks, threads, 0, stream>>>(
      update, snapshot, out);
}

// Round 3
// 99.827 us; speedup vs baseline: 1.0231x; 1.0231x over previous
//
#include <hip/hip_runtime.h>

// Problem constants (from reference)
#define UPDATE_SIZE 4096
#define BATCH 256
#define NUM_UPDATES 8
#define NUM_CH 2
#define KEEP (NUM_UPDATES * UPDATE_SIZE)               // 32768
#define SNAP ((BATCH + NUM_UPDATES - 1) * UPDATE_SIZE) // 1077248
#define OUT_LEN (BATCH * UPDATE_SIZE)                  // 1048576 = 2^20

// float4-unit constants
#define OUT4 (OUT_LEN / 4)            // 262144 = 2^18
#define SNAP4 (SNAP / 4)              // 269312
#define REST4 ((SNAP - OUT_LEN) / 4)  // 7168
#define ROW4 (KEEP / 4)               // 8192 float4 per (b,c) update row
#define UPD4 (UPDATE_SIZE / 4)        // 1024
#define TOTAL4 (2 * OUT4 + 2 * SNAP4) // 1062912 = 4152 * 256

// 4 independent coalesced streams per thread (64 B stored / thread)
#define KPT 4
#define NTHREADS (TOTAL4 / KPT)       // 265728 = 1038 * 256
// Region boundaries (in float4 units) are all multiples of 64, and NTHREADS
// is a multiple of 64 -> every wave is region-uniform for each k (no divergence).

typedef float f32x4 __attribute__((ext_vector_type(4)));  // native vec: ok for nontemporal builtins

__device__ __forceinline__ f32x4 compute_elem(int idx,
                                              const f32x4* __restrict__ up4,
                                              const f32x4* __restrict__ sn4) {
  int c, s4;
  if (idx < 2 * OUT4) {
    c = idx >> 18;             // / OUT4
    s4 = idx & (OUT4 - 1);
  } else {
    const int r = idx - 2 * OUT4;
    c = (r >= SNAP4) ? 1 : 0;
    const int t4 = r - c * SNAP4;
    if (t4 >= REST4) {
      return (f32x4){0.f, 0.f, 0.f, 0.f};     // zero-pad of new_snapshot
    }
    s4 = OUT4 + t4;
  }

  f32x4 acc = sn4[c * SNAP4 + s4];
  const int q = s4 >> 10;      // window index, uniform over the 4 packed floats
  if (q >= 7 && q < BATCH) {
    // interior: exactly 8 covering windows
    #pragma unroll
    for (int k = 0; k < 8; ++k) {
      const int b = q - 7 + k;
      acc += 0.125f * up4[(b * NUM_CH + c) * ROW4 + (s4 - b * UPD4)];
    }
  } else {
    const int blo = (q >= 7) ? (q - 7) : 0;
    const int bhi = (q < BATCH) ? q : (BATCH - 1);
    for (int b = blo; b <= bhi; ++b) {
      acc += 0.125f * up4[(b * NUM_CH + c) * ROW4 + (s4 - b * UPD4)];
    }
  }
  return acc;
}

__global__ __launch_bounds__(256) void OnlineAverager_62680752718461_kernel(
    const float* __restrict__ update,
    const float* __restrict__ snapshot,
    float* __restrict__ out) {
  const int tid = blockIdx.x * blockDim.x + threadIdx.x;

  const f32x4* __restrict__ up4 = reinterpret_cast<const f32x4*>(update);
  const f32x4* __restrict__ sn4 = reinterpret_cast<const f32x4*>(snapshot);
  f32x4* __restrict__ o4 = reinterpret_cast<f32x4*>(out);

  // 4 independent, fully-coalesced streams: idx = tid + k*NTHREADS.
  // Unrolled so the compiler can interleave all ~36 loads for MLP.
  #pragma unroll
  for (int k = 0; k < KPT; ++k) {
    const int idx = tid + k * NTHREADS;
    const f32x4 acc = compute_elem(idx, up4, sn4);
    __builtin_nontemporal_store(acc, &o4[idx]);  // stream-once output
  }
}

extern "C" void kernel_launch(void* const* d_in, const int* in_sizes, int n_in,
                              void* d_out, int out_size, void* d_ws, size_t ws_size,
                              hipStream_t stream) {
  const float* update = (const float*)d_in[0];   // (256, 2, 32768) f32
  const float* snapshot = (const float*)d_in[1]; // (2, 1077248) f32
  float* out = (float*)d_out;                    // (1,2,2^20) ++ (2,SNAP) f32

  const int threads = 256;
  const int blocks = NTHREADS / threads;         // 1038
  OnlineAverager_62680752718461_kernel<<<blocks, threads, 0, stream>>>(
      update, snapshot, out);
}